// Round 1
// baseline (279.776 us; speedup 1.0000x reference)
//
#include <hip/hip_runtime.h>
#include <math.h>

#define HH 384
#define WW 384
#define NIMG 272                       // 16 * 17
#define IMG_STRIDE (HH * WW)
#define ROWS 16                        // output rows per thread (column strip)
#define STRIPS (HH / ROWS)             // 24
#define C4N (WW / 4)                   // 96 float4 groups per row
#define UNITS_PER_IMG (C4N * STRIPS)   // 2304
#define TOTAL_UNITS (UNITS_PER_IMG * NIMG)  // 626688
#define BLOCK 256
#define NBLOCKS (TOTAL_UNITS / BLOCK)  // 2448 (multiple of 8 -> simple XCD swizzle)
#define NXCD 8

typedef float f4_t __attribute__((ext_vector_type(4)));

__device__ __forceinline__ float max3f(float a, float b, float c) {
    return fmaxf(fmaxf(a, b), c);      // -> v_max3_f32
}
__device__ __forceinline__ float fast_sigmoid(float v) {
    return __fdividef(1.0f, 1.0f + __expf(-v));
}

// Register-streaming 3x3 peak extraction: each thread owns a 4-wide column
// strip and rolls a 3-row horizontal-max window down ROWS rows. No LDS, no
// barriers — vertical reuse lives in 3 f4 registers; horizontal reuse comes
// from the L1 (edge scalars overlap neighbor lanes' float4 lines).
__global__ __launch_bounds__(BLOCK) void
heatmap_peaks_stream(const float* __restrict__ in, float* __restrict__ out) {
    const float NEG = -INFINITY;
    const f4_t NEG4 = {NEG, NEG, NEG, NEG};

    // XCD-aware bijective swizzle: strips sharing halo rows land on the same
    // XCD's L2 (NBLOCKS % 8 == 0 so the simple form is bijective).
    int bid = blockIdx.x;
    int swz = (bid % NXCD) * (NBLOCKS / NXCD) + bid / NXCD;

    int u   = swz * BLOCK + (int)threadIdx.x;
    int c4  = u % C4N;                 // float4 column group, fastest -> coalesced
    int t   = u / C4N;
    int s   = t % STRIPS;
    int img = t / STRIPS;
    int y0  = s * ROWS;

    const float* ib = in  + (size_t)img * IMG_STRIDE + c4 * 4;
    float*       ob = out + (size_t)img * IMG_STRIDE + (size_t)y0 * WW + c4 * 4;

    const bool has_l = (c4 > 0);
    const bool has_r = (c4 < C4N - 1);
    const int  loff  = has_l ? -1 : 0;     // clamped (always-valid) addresses,
    const int  roff  = has_r ?  4 : 3;     // select NEG afterwards: branchless

    // load one input row: aligned float4 + left/right edge scalars
    auto ldrow = [&](int gy, f4_t& v, float& l, float& r) {
        const float* p = ib + (size_t)gy * WW;
        v = *(const f4_t*)p;
        float lv = p[loff];
        float rv = p[roff];
        l = has_l ? lv : NEG;
        r = has_r ? rv : NEG;
    };
    // horizontal 3-max for 4 consecutive pixels
    auto hmax = [&](f4_t v, float l, float r) -> f4_t {
        f4_t h;
        h.x = max3f(l,   v.x, v.y);
        h.y = max3f(v.x, v.y, v.z);
        h.z = max3f(v.y, v.z, v.w);
        h.w = max3f(v.z, v.w, r);
        return h;
    };
    // finish one output row: vertical 3-max of rolling hmaxes + sigmoid gate
    auto emit = [&](int j, f4_t v, f4_t a, f4_t b, f4_t c) {
        f4_t o; float m, pp;
        m = max3f(a.x, b.x, c.x); pp = fast_sigmoid(v.x);
        o.x = (m == v.x && pp > 0.05f) ? pp : 0.0f;
        m = max3f(a.y, b.y, c.y); pp = fast_sigmoid(v.y);
        o.y = (m == v.y && pp > 0.05f) ? pp : 0.0f;
        m = max3f(a.z, b.z, c.z); pp = fast_sigmoid(v.z);
        o.z = (m == v.z && pp > 0.05f) ? pp : 0.0f;
        m = max3f(a.w, b.w, c.w); pp = fast_sigmoid(v.w);
        o.w = (m == v.w && pp > 0.05f) ? pp : 0.0f;
        // output never re-read: keep L1/L2 for the input stream
        __builtin_nontemporal_store(o, (f4_t*)(ob + (size_t)j * WW));
    };

    f4_t hm_prev, hm_cur, val_cur;

    // row y0-1 (top halo; -inf outside the image == SAME padding w/ -inf init)
    {
        f4_t v; float l, r;
        int gy = (y0 > 0) ? y0 - 1 : 0;
        ldrow(gy, v, l, r);
        if (y0 == 0) { v = NEG4; l = NEG; r = NEG; }
        hm_prev = hmax(v, l, r);
    }
    // row y0
    {
        f4_t v; float l, r;
        ldrow(y0, v, l, r);
        hm_cur  = hmax(v, l, r);
        val_cur = v;
    }
    // stage row y0+1 (always in-image: y0 <= 368)
    f4_t vA; float lA, rA;
    ldrow(y0 + 1, vA, lA, rA);

    // main loop: stage row j+2 while finishing row j (depth-1 reg pipeline);
    // rows y0+2 .. y0+ROWS-1 are always in-image -> no per-iter conditionals
#pragma unroll 4
    for (int j = 0; j <= ROWS - 3; ++j) {
        f4_t vB; float lB, rB;
        ldrow(y0 + j + 2, vB, lB, rB);
        f4_t hm_next = hmax(vA, lA, rA);
        emit(j, val_cur, hm_prev, hm_cur, hm_next);
        hm_prev = hm_cur; hm_cur = hm_next; val_cur = vA;
        vA = vB; lA = lB; rA = rB;
    }
    // j = ROWS-2: stage bottom halo row y0+ROWS (or -inf at image bottom)
    {
        f4_t vB; float lB, rB;
        bool valid = (y0 + ROWS < HH);
        int gy = valid ? y0 + ROWS : HH - 1;
        ldrow(gy, vB, lB, rB);
        if (!valid) { vB = NEG4; lB = NEG; rB = NEG; }
        f4_t hm_next = hmax(vA, lA, rA);
        emit(ROWS - 2, val_cur, hm_prev, hm_cur, hm_next);
        hm_prev = hm_cur; hm_cur = hm_next; val_cur = vA;
        vA = vB; lA = lB; rA = rB;
    }
    // j = ROWS-1: last output row of the strip
    {
        f4_t hm_next = hmax(vA, lA, rA);
        emit(ROWS - 1, val_cur, hm_prev, hm_cur, hm_next);
    }
}

extern "C" void kernel_launch(void* const* d_in, const int* in_sizes, int n_in,
                              void* d_out, int out_size, void* d_ws, size_t ws_size,
                              hipStream_t stream) {
    const float* in = (const float*)d_in[0];
    float* out = (float*)d_out;
    heatmap_peaks_stream<<<NBLOCKS, BLOCK, 0, stream>>>(in, out);
}

// Round 2
// 275.913 us; speedup vs baseline: 1.0140x; 1.0140x over previous
//
#include <hip/hip_runtime.h>
#include <math.h>

#define HH 384
#define WW 384
#define NIMG 272                        // 16 * 17
#define IMG_STRIDE (HH * WW)
#define ROWS 8                          // output rows per thread
#define NROWLD (ROWS + 2)               // 10 rows loaded (incl. halo)
#define STRIPS (HH / ROWS)              // 48
#define C4N (WW / 4)                    // 96 float4 groups per row
#define BLOCK 256
#define NBLOCKS (NIMG * STRIPS * C4N / BLOCK)   // 4896, % 8 == 0
#define NXCD 8

typedef float f4_t __attribute__((ext_vector_type(4)));

__device__ __forceinline__ float max3f(float a, float b, float c) {
    return fmaxf(fmaxf(a, b), c);       // -> v_max3_f32
}
__device__ __forceinline__ float fast_sigmoid(float v) {
    return __fdividef(1.0f, 1.0f + __expf(-v));
}

// Batch-load register kernel: each thread owns a 4-wide, 8-row column strip.
// ALL 10 row-loads (float4 + 2 edge scalars = 30 loads) are issued up front
// into distinct registers -> 30-deep MLP per lane, no LDS, no barriers, no
// rolling load->use chain (the round-1 regression: depth-1 pipeline, 3 loads
// in flight, latency-bound at 30% HBM BW).
__global__ __launch_bounds__(BLOCK) void
heatmap_peaks_batch(const float* __restrict__ in, float* __restrict__ out) {
    const float NEG = -INFINITY;
    const f4_t NEG4 = {NEG, NEG, NEG, NEG};

    // XCD-aware bijective swizzle (NBLOCKS % 8 == 0): strips sharing halo
    // rows land on the same XCD's L2.
    int bid = blockIdx.x;
    int swz = (bid % NXCD) * (NBLOCKS / NXCD) + bid / NXCD;

    int u   = swz * BLOCK + (int)threadIdx.x;
    int c4  = u % C4N;                  // fastest -> coalesced float4 loads
    int t   = u / C4N;
    int s   = t % STRIPS;
    int img = t / STRIPS;
    int y0  = s * ROWS;

    const float* ib = in  + (size_t)img * IMG_STRIDE + c4 * 4;
    float*       ob = out + (size_t)img * IMG_STRIDE + (size_t)y0 * WW + c4 * 4;

    const bool has_l = (c4 > 0);
    const bool has_r = (c4 < C4N - 1);
    const int  loff  = has_l ? -1 : 0;  // clamped, always-valid addresses
    const int  roff  = has_r ?  4 : 3;

    // ---- phase 1: issue all 30 independent loads (no waits between) ----
    f4_t v[NROWLD]; float l[NROWLD], r[NROWLD];
#pragma unroll
    for (int k = 0; k < NROWLD; ++k) {
        int gy = y0 - 1 + k;
        int cy = gy < 0 ? 0 : (gy > HH - 1 ? HH - 1 : gy);  // clamp addr
        const float* p = ib + (size_t)cy * WW;
        v[k] = *(const f4_t*)p;
        l[k] = p[loff];
        r[k] = p[roff];
    }

    // ---- phase 2: boundary fixups (cndmask after load, waits descend) ----
#pragma unroll
    for (int k = 0; k < NROWLD; ++k) {
        if (!has_l) l[k] = NEG;
        if (!has_r) r[k] = NEG;
    }
    if (y0 == 0)            { v[0] = NEG4;          l[0] = NEG;          r[0] = NEG; }
    if (y0 + ROWS == HH)    { v[NROWLD-1] = NEG4;   l[NROWLD-1] = NEG;   r[NROWLD-1] = NEG; }

    // ---- phase 3: horizontal 3-max per row (frees l/r) ----
    f4_t h[NROWLD];
#pragma unroll
    for (int k = 0; k < NROWLD; ++k) {
        h[k].x = max3f(l[k],   v[k].x, v[k].y);
        h[k].y = max3f(v[k].x, v[k].y, v[k].z);
        h[k].z = max3f(v[k].y, v[k].z, v[k].w);
        h[k].w = max3f(v[k].z, v[k].w, r[k]);
    }

    // ---- phase 4: vertical 3-max + sigmoid gate + store, one row at a time ----
#pragma unroll
    for (int j = 0; j < ROWS; ++j) {
        f4_t c = v[j + 1];              // center values of output row j
        f4_t o; float m, p;
        m = max3f(h[j].x, h[j+1].x, h[j+2].x); p = fast_sigmoid(c.x);
        o.x = (m == c.x && p > 0.05f) ? p : 0.0f;
        m = max3f(h[j].y, h[j+1].y, h[j+2].y); p = fast_sigmoid(c.y);
        o.y = (m == c.y && p > 0.05f) ? p : 0.0f;
        m = max3f(h[j].z, h[j+1].z, h[j+2].z); p = fast_sigmoid(c.z);
        o.z = (m == c.z && p > 0.05f) ? p : 0.0f;
        m = max3f(h[j].w, h[j+1].w, h[j+2].w); p = fast_sigmoid(c.w);
        o.w = (m == c.w && p > 0.05f) ? p : 0.0f;
        // output never re-read: keep L1/L2/L3 for the input stream
        __builtin_nontemporal_store(o, (f4_t*)(ob + (size_t)j * WW));
    }
}

extern "C" void kernel_launch(void* const* d_in, const int* in_sizes, int n_in,
                              void* d_out, int out_size, void* d_ws, size_t ws_size,
                              hipStream_t stream) {
    const float* in = (const float*)d_in[0];
    float* out = (float*)d_out;
    heatmap_peaks_batch<<<NBLOCKS, BLOCK, 0, stream>>>(in, out);
}

// Round 3
// 275.554 us; speedup vs baseline: 1.0153x; 1.0013x over previous
//
#include <hip/hip_runtime.h>
#include <math.h>

#define HH 384
#define WW 384
#define NIMG 272                        // 16 * 17
#define IMG_STRIDE (HH * WW)
#define ROWS 8                          // output rows per thread
#define NROWLD (ROWS + 2)               // 10 rows live (incl. halo)
#define STRIPS (HH / ROWS)              // 48
#define C4N (WW / 4)                    // 96 float4 groups per row
#define BLOCK 256
#define NBLOCKS (NIMG * STRIPS * C4N / BLOCK)   // 4896, % 8 == 0
#define NXCD 8

typedef float f4_t __attribute__((ext_vector_type(4)));

__device__ __forceinline__ float max3f(float a, float b, float c) {
    return fmaxf(fmaxf(a, b), c);       // -> v_max3_f32
}
__device__ __forceinline__ float fast_sigmoid(float v) {
    return __fdividef(1.0f, 1.0f + __expf(-v));
}

// Round-3: batch-register kernel with shuffle-sourced horizontal halo.
// Per lane: 10 float4 loads, zero scalar loads (was 30 vmem: the 20 per-lane
// edge-dword gathers cost TA slots + latency depth for 4B each). Lanes hold
// consecutive c4 groups of the same strip row, so the left/right halo scalars
// are v.w of lane-1 / v.x of lane+1 -> __shfl (DS pipe, otherwise idle).
// Only lane 0/63 per wave touch memory for edges (exec-masked, 2 instr/wave).
// __launch_bounds__(256,4): VGPR cap 128 so the 10-load batch survives
// regalloc as one vmcnt-descending cluster (round-1/2 were issue/MLP-bound:
// HBM 30%, VALU 22%, occ 50% -- everything idle).
__global__ __launch_bounds__(BLOCK, 4) void
heatmap_peaks_shfl(const float* __restrict__ in, float* __restrict__ out) {
    const float NEG = -INFINITY;
    const f4_t NEG4 = {NEG, NEG, NEG, NEG};

    // XCD-aware bijective swizzle (NBLOCKS % 8 == 0)
    int bid = blockIdx.x;
    int swz = (bid % NXCD) * (NBLOCKS / NXCD) + bid / NXCD;

    int u    = swz * BLOCK + (int)threadIdx.x;
    int lane = (int)threadIdx.x & 63;

    int c4  = u % C4N;                  // fastest -> coalesced float4 loads
    int t   = u / C4N;
    int s   = t % STRIPS;
    int img = t / STRIPS;
    int y0  = s * ROWS;

    const float* ib = in  + (size_t)img * IMG_STRIDE + c4 * 4;
    float*       ob = out + (size_t)img * IMG_STRIDE + (size_t)y0 * WW + c4 * 4;

    const bool has_l = (c4 > 0);
    const bool has_r = (c4 < C4N - 1);

    // ---- phase 1: 10 independent float4 loads, issued back-to-back ----
    f4_t v[NROWLD];
#pragma unroll
    for (int k = 0; k < NROWLD; ++k) {
        int gy = y0 - 1 + k;
        int cy = gy < 0 ? 0 : (gy > HH - 1 ? HH - 1 : gy);  // clamped addr
        v[k] = *(const f4_t*)(ib + (size_t)cy * WW);
    }

    // ---- wave-edge scalars: only lane 0 / lane 63 hit memory ----
    float el[NROWLD], er[NROWLD];
    if (lane == 0 && has_l) {
#pragma unroll
        for (int k = 0; k < NROWLD; ++k) {
            int gy = y0 - 1 + k;
            int cy = gy < 0 ? 0 : (gy > HH - 1 ? HH - 1 : gy);
            el[k] = ib[(size_t)cy * WW - 1];
        }
    }
    if (lane == 63 && has_r) {
#pragma unroll
        for (int k = 0; k < NROWLD; ++k) {
            int gy = y0 - 1 + k;
            int cy = gy < 0 ? 0 : (gy > HH - 1 ? HH - 1 : gy);
            er[k] = ib[(size_t)cy * WW + 4];
        }
    }

    const bool topdead = (y0 == 0);
    const bool botdead = (y0 + ROWS == HH);
    if (topdead) v[0] = NEG4;                 // SAME padding == -inf halo
    if (botdead) v[NROWLD - 1] = NEG4;

    // ---- phase 2: horizontal 3-max; halo scalars via cross-lane shuffle ----
    f4_t h[NROWLD];
#pragma unroll
    for (int k = 0; k < NROWLD; ++k) {
        float lw = __shfl_up(v[k].w, 1);      // left neighbor's last px
        float rx = __shfl_down(v[k].x, 1);    // right neighbor's first px
        float lv = (lane == 0)  ? el[k] : lw; // wave-boundary fixup
        float rv = (lane == 63) ? er[k] : rx;
        bool rowdead = (k == 0 && topdead) || (k == NROWLD - 1 && botdead);
        float L = (has_l && !rowdead) ? lv : NEG;
        float R = (has_r && !rowdead) ? rv : NEG;
        h[k].x = max3f(L,      v[k].x, v[k].y);
        h[k].y = max3f(v[k].x, v[k].y, v[k].z);
        h[k].z = max3f(v[k].y, v[k].z, v[k].w);
        h[k].w = max3f(v[k].z, v[k].w, R);
    }

    // ---- phase 3: vertical 3-max + sigmoid gate + NT store ----
#pragma unroll
    for (int j = 0; j < ROWS; ++j) {
        f4_t c = v[j + 1];                    // center values of output row j
        f4_t o; float m, p;
        m = max3f(h[j].x, h[j+1].x, h[j+2].x); p = fast_sigmoid(c.x);
        o.x = (m == c.x && p > 0.05f) ? p : 0.0f;
        m = max3f(h[j].y, h[j+1].y, h[j+2].y); p = fast_sigmoid(c.y);
        o.y = (m == c.y && p > 0.05f) ? p : 0.0f;
        m = max3f(h[j].z, h[j+1].z, h[j+2].z); p = fast_sigmoid(c.z);
        o.z = (m == c.z && p > 0.05f) ? p : 0.0f;
        m = max3f(h[j].w, h[j+1].w, h[j+2].w); p = fast_sigmoid(c.w);
        o.w = (m == c.w && p > 0.05f) ? p : 0.0f;
        // output never re-read: keep L1/L2/L3 for the input stream
        __builtin_nontemporal_store(o, (f4_t*)(ob + (size_t)j * WW));
    }
}

extern "C" void kernel_launch(void* const* d_in, const int* in_sizes, int n_in,
                              void* d_out, int out_size, void* d_ws, size_t ws_size,
                              hipStream_t stream) {
    const float* in = (const float*)d_in[0];
    float* out = (float*)d_out;
    heatmap_peaks_shfl<<<NBLOCKS, BLOCK, 0, stream>>>(in, out);
}

// Round 4
// 272.987 us; speedup vs baseline: 1.0249x; 1.0094x over previous
//
#include <hip/hip_runtime.h>
#include <math.h>

#define HH 384
#define WW 384
#define NIMG 272                         // 16 * 17
#define IMG_STRIDE (HH * WW)
#define TW 64
#define TH 64
#define TX 6
#define TY 6
#define NBLOCKS (TX * TY * NIMG)         // 9792, % 8 == 0
#define NXCD 8
#define LDS_W 72                         // 18 f4/row; row = 288 B (16B-aligned)
#define LDS_H 66                         // y0-1 .. y0+64
#define ROW_F4 18
#define NL4 (LDS_H * ROW_F4)             // 1188 f4 stage units per block
#define NLD 5                            // ceil(1188 / 256)

typedef float f4_t __attribute__((ext_vector_type(4)));

__device__ __forceinline__ float max3f(float a, float b, float c) {
    return fmaxf(fmaxf(a, b), c);        // -> v_max3_f32
}
__device__ __forceinline__ float fast_sigmoid(float v) {
    return __fdividef(1.0f, 1.0f + __expf(-v));
}

// Round-4: the round-0 LDS structure (best measured: ~89us) with its three
// weaknesses fixed. (1) staging is 5 independent float4 loads/lane (1188
// dwordx4/block, columns x0-4..x0+67 so every f4 is 16B-aligned and wholly
// in/out of the image) instead of 18 scalar dwords -- the load->LDS pattern
// is the one batch hipcc provably keeps in flight (regalloc destroyed the
// register-resident batches of rounds 1-3: VGPR capped at 40-48, MLP ~2).
// (2) compute mapping is one COLUMN x 16 rows per thread: a wave's 64 lanes
// read 64 consecutive LDS floats -> 2 lanes/bank = conflict-free (the 4x4
// block mapping concentrated 64 lanes onto 8 banks). (3) XCD-aware swizzle.
__global__ __launch_bounds__(256, 4) void
heatmap_peaks_tile(const float* __restrict__ in, float* __restrict__ out) {
    __shared__ float S[LDS_H * LDS_W];
    const float NEG = -INFINITY;
    const f4_t NEG4 = {NEG, NEG, NEG, NEG};

    int tid = (int)threadIdx.x;
    int bid = (int)blockIdx.x;
    int swz = (bid % NXCD) * (NBLOCKS / NXCD) + bid / NXCD;

    int txt = swz % TX;
    int tmp = swz / TX;
    int tyt = tmp % TY;
    int img = tmp / TY;
    int x0  = txt * TW;
    int y0  = tyt * TH;

    const float* ib = in + (size_t)img * IMG_STRIDE;

    // ---- stage: 5 independent f4 loads issued before any wait ----
    f4_t va[NLD];
    int  la[NLD];
    bool act[NLD];
#pragma unroll
    for (int k = 0; k < NLD; ++k) {
        int e   = tid + k * 256;
        int row = e / ROW_F4;            // magic-mul, no HW div
        int c4  = e - row * ROW_F4;
        int gy  = y0 - 1 + row;
        int gx  = x0 - 4 + c4 * 4;       // 16B-aligned f4 column start
        bool vy = (unsigned)gy < (unsigned)HH;
        bool vx = (unsigned)gx <= (unsigned)(WW - 4);  // f4 wholly in image
        bool inr = (e < NL4);
        int cy = vy ? gy : 0;            // clamped, always-valid address
        int cx = vx ? gx : 0;
        f4_t v = *(const f4_t*)(ib + (size_t)cy * WW + cx);
        va[k]  = (vx && vy && inr) ? v : NEG4;
        la[k]  = row * LDS_W + c4 * 4;
        act[k] = inr;
    }
#pragma unroll
    for (int k = 0; k < NLD; ++k)
        if (act[k]) *(f4_t*)&S[la[k]] = va[k];   // ds_write_b128, aligned
    __syncthreads();

    // ---- compute: thread = 1 column x 16 rows; lanes -> consecutive cols ----
    int c  = tid & 63;                   // column within tile
    int q  = tid >> 6;                   // row quarter (0..3)
    int lc = 4 + c;                      // LDS col of this thread's column
    int rbase = q * 16;                  // LDS row of (first output row - 1)

    float h[18], val[18];
#pragma unroll
    for (int j = 0; j < 18; ++j) {
        const float* row = &S[(rbase + j) * LDS_W + lc];
        float l = row[-1];               // lanes stride-1 -> 2/bank, free
        float m = row[0];
        float r = row[1];
        h[j]   = max3f(l, m, r);
        val[j] = m;
    }

    float* ob = out + (size_t)img * IMG_STRIDE
                    + (size_t)(y0 + rbase) * WW + x0 + c;
#pragma unroll
    for (int j = 0; j < 16; ++j) {
        float m = max3f(h[j], h[j + 1], h[j + 2]);
        float v = val[j + 1];
        float p = fast_sigmoid(v);
        float o = (m == v && p > 0.05f) ? p : 0.0f;
        // 64 lanes -> 256B contiguous; output never re-read: NT store
        __builtin_nontemporal_store(o, ob + (size_t)j * WW);
    }
}

extern "C" void kernel_launch(void* const* d_in, const int* in_sizes, int n_in,
                              void* d_out, int out_size, void* d_ws, size_t ws_size,
                              hipStream_t stream) {
    const float* in = (const float*)d_in[0];
    float* out = (float*)d_out;
    heatmap_peaks_tile<<<NBLOCKS, 256, 0, stream>>>(in, out);
}

// Round 7
// 270.973 us; speedup vs baseline: 1.0325x; 1.0074x over previous
//
#include <hip/hip_runtime.h>
#include <math.h>

#define HH 384
#define WW 384
#define NIMG 272
#define IMG_STRIDE (HH * WW)
#define NTOT ((long)NIMG * IMG_STRIDE)      // 40,108,032 floats
#define TW 64
#define TH 64
#define TX 6
#define TY 6
#define NBLOCKS (TX * TY * NIMG)            // 9792, % 8 == 0
#define NXCD 8
#define LDS_W 68                            // x0-1 .. x0+66 = 17 f4 chunks, NO pad
#define NDMA 18                             // 18 instrs * 64 lanes * 16 B = 18432 B

typedef float f4_t __attribute__((ext_vector_type(4)));

__device__ __forceinline__ float max3f(float a, float b, float c) {
    return fmaxf(fmaxf(a, b), c);           // -> v_max3_f32
}
__device__ __forceinline__ float fast_sigmoid(float v) {
    return __fdividef(1.0f, 1.0f + __expf(-v));
}

// Round-7: round-5/6 DMA kernel + the missing top-left clamp fixup.
// r6 failed (absmax 0.88): for img=0,y0=0,x0=0, chunk (row=1,cin=0) has
// gidx=-1 clamped to 0, so live LDS row-1 cols 1..3 got in[1..3] instead of
// in[0..2] (every other clamp case only corrupts dead halo cells; the
// symmetric NTOT-end clamp already had its fixup). Fix: one-thread LDS
// patch of those 3 floats between the existing barriers. Staging structure
// unchanged: 18 global_load_lds dwordx4 per block (no VGPR round-trip ->
// regalloc cannot re-cluster the batch; single vmcnt drain at the barrier),
// testing the theory that all register-staged variants (r1-r4, 89-104us)
// serialize on ~2-3 loads-in-flight x ~900cy HBM latency.
__global__ __launch_bounds__(256, 6) void
heatmap_peaks_dma(const float* __restrict__ in, float* __restrict__ out) {
    __shared__ float S[NDMA * 256];         // 4608 floats; rows 66,67 junk
    const float NEG = -INFINITY;
    const f4_t NEG4 = {NEG, NEG, NEG, NEG};

    int tid  = (int)threadIdx.x;
    int lane = tid & 63;
    int wid  = tid >> 6;

    int bid = (int)blockIdx.x;
    int swz = (bid % NXCD) * (NBLOCKS / NXCD) + bid / NXCD;  // bijective
    int txt = swz % TX;
    int tmp = swz / TX;
    int tyt = tmp % TY;
    int img = tmp / TY;
    int x0  = txt * TW;
    int y0  = tyt * TH;

    // ---- stage 66x68 tile via DMA: LDS chunk c=i*64+lane <-> floats
    // [68*row + 4*cin], row=c/17, cin=c%17; global (y0-1+row, x0-1+4cin) ----
#pragma unroll
    for (int i = 0; i < NDMA; ++i) {
        if ((i & 3) != wid) continue;       // wave-uniform split: 5/5/4/4
        int chunk    = i * 64 + lane;
        unsigned row = (unsigned)chunk / 17u;      // magic-mul
        int cin      = chunk - (int)row * 17;
        int gy       = y0 - 1 + (int)row;
        gy = gy < 0 ? 0 : (gy > HH - 1 ? HH - 1 : gy);
        long gidx = (long)img * IMG_STRIDE
                  + (long)gy * WW + (x0 - 1 + 4 * cin);
        // contiguous 16B loads: a x0-1 start pulls the previous row's last
        // element into a DEAD LDS cell, live cells stay correct -- except
        // the two buffer-end clamps below, each patched between barriers.
        gidx = gidx < 0 ? 0 : (gidx > NTOT - 4 ? NTOT - 4 : gidx);
        __builtin_amdgcn_global_load_lds(
            (const __attribute__((address_space(1))) void*)(in + gidx),
            (__attribute__((address_space(3))) void*)(S + i * 256),
            16, 0, 0);
    }
    __syncthreads();                        // single vmcnt(0) drain + barrier
    // clamp fixup 1 (gidx=-1 -> 0): img 0, top-left tile, LDS row 1 (gy=0)
    // cols 1..3 must hold in[0..2] (DMA delivered in[1..3] there).
    if (img == 0 && tyt == 0 && txt == 0 && tid == 0) {
        S[LDS_W + 1] = in[0];
        S[LDS_W + 2] = in[1];
        S[LDS_W + 3] = in[2];
    }
    // clamp fixup 2 (gidx=NTOT-1 -> NTOT-4): last image, bottom-right tile,
    // LDS (row 64, col 64) must hold in[NTOT-1] (DMA delivered in[NTOT-4]).
    if (img == NIMG - 1 && tyt == TY - 1 && txt == TX - 1 && tid == 0)
        S[64 * LDS_W + 64] = in[NTOT - 1];
    __syncthreads();

    // ---- compute: thread = f4-col x 4 rows; rolling 3-row hmax window ----
    int fx = tid & 15;                      // out cols 4fx..4fx+3
    int ry = tid >> 4;                      // out rows 4ry..4ry+3
    const float* Sb = S + ry * 4 * LDS_W + fx * 4;
    const bool ldead = (fx == 0      && x0 == 0);
    const bool rdead = (fx == 15     && x0 == WW - TW);
    const bool tdead = (ry == 0      && y0 == 0);
    const bool bdead = (ry == 15     && y0 == HH - TH);

    auto hrow = [&](int j, f4_t& val) -> f4_t {   // LDS row 4ry+j
        const float* p = Sb + j * LDS_W;
        f4_t  b  = *(const f4_t*)p;         // aligned b128: cols 4fx..4fx+3
        float c3 = p[4];
        float rr = p[5];
        float vl = ldead ? NEG : b.x;       // left halo (col 4fx)
        float vr = rdead ? NEG : rr;        // right halo (col 4fx+5)
        val.x = b.y; val.y = b.z; val.z = b.w; val.w = c3;
        f4_t h;
        h.x = max3f(vl,  b.y, b.z);
        h.y = max3f(b.y, b.z, b.w);
        h.z = max3f(b.z, b.w, c3);
        h.w = max3f(b.w, c3,  vr);
        return h;
    };

    f4_t vdum;
    f4_t hA = hrow(0, vdum);                // LDS row 4ry   (top of window)
    if (tdead) hA = NEG4;                   // y0-1 doesn't exist at image top
    f4_t vB;
    f4_t hB = hrow(1, vB);                  // center row of first output

    float* ob = out + (size_t)img * IMG_STRIDE
                    + (size_t)(y0 + ry * 4) * WW + x0 + fx * 4;
#pragma unroll
    for (int j = 0; j < 4; ++j) {
        f4_t vC;
        f4_t hC = hrow(j + 2, vC);
        if (j == 3 && bdead) hC = NEG4;     // y0+64 doesn't exist at bottom
        f4_t o; float m, p;
        m = max3f(hA.x, hB.x, hC.x); p = fast_sigmoid(vB.x);
        o.x = (m == vB.x && p > 0.05f) ? p : 0.0f;
        m = max3f(hA.y, hB.y, hC.y); p = fast_sigmoid(vB.y);
        o.y = (m == vB.y && p > 0.05f) ? p : 0.0f;
        m = max3f(hA.z, hB.z, hC.z); p = fast_sigmoid(vB.z);
        o.z = (m == vB.z && p > 0.05f) ? p : 0.0f;
        m = max3f(hA.w, hB.w, hC.w); p = fast_sigmoid(vB.w);
        o.w = (m == vB.w && p > 0.05f) ? p : 0.0f;
        *(f4_t*)(ob + (size_t)j * WW) = o;  // plain f4 store
        hA = hB; hB = hC; vB = vC;
    }
}

extern "C" void kernel_launch(void* const* d_in, const int* in_sizes, int n_in,
                              void* d_out, int out_size, void* d_ws, size_t ws_size,
                              hipStream_t stream) {
    const float* in = (const float*)d_in[0];
    float* out = (float*)d_out;
    heatmap_peaks_dma<<<NBLOCKS, 256, 0, stream>>>(in, out);
}